// Round 1
// 347.435 us; speedup vs baseline: 1.0724x; 1.0724x over previous
//
#include <hip/hip_runtime.h>

using bf16x8 = __attribute__((ext_vector_type(8))) __bf16;
using f32x4  = __attribute__((ext_vector_type(4))) float;

#define C_ 64
#define S_ 128
#define H_ 2048
#define M_ 8192

__device__ __forceinline__ unsigned short f2bf(float f) {
  unsigned u = __float_as_uint(f);
  u = u + 0x7fffu + ((u >> 16) & 1u);   // RNE
  return (unsigned short)(u >> 16);
}
__device__ __forceinline__ float bf2f(unsigned short h) {
  return __uint_as_float(((unsigned)h) << 16);
}

// async global->LDS, 16 B per lane; LDS dest = uniform base + lane*16
__device__ __forceinline__ void glds16(const unsigned short* g, unsigned short* l) {
  __builtin_amdgcn_global_load_lds(
      (const __attribute__((address_space(1))) void*)g,
      (__attribute__((address_space(3))) void*)l, 16, 0, 0);
}

// ---- fused: split x (blocks 0..16383) | split+transpose W (16384..17407) | zero G ----
__global__ void k_split_all(const float* __restrict__ x,
                            unsigned short* __restrict__ xh,
                            unsigned short* __restrict__ xl,
                            const float* __restrict__ W,
                            unsigned short* __restrict__ Wth,
                            unsigned short* __restrict__ Wtl,
                            float* __restrict__ G) {
  __shared__ float Ts[64][68];
  const int b = blockIdx.x;
  const int t = threadIdx.x;
  if (b < 16384) {
    int idx = b * 256 + t;
    float4 v = ((const float4*)x)[idx];
    float a[4] = {v.x, v.y, v.z, v.w};
    unsigned short h[4], l[4];
#pragma unroll
    for (int q = 0; q < 4; ++q) {
      h[q] = f2bf(a[q]);
      l[q] = f2bf(a[q] - bf2f(h[q]));
    }
    ((ushort4*)xh)[idx] = make_ushort4(h[0], h[1], h[2], h[3]);
    ((ushort4*)xl)[idx] = make_ushort4(l[0], l[1], l[2], l[3]);
  } else if (b < 17408) {
    const int bb = b - 16384;
    const int k0 = (bb & 31) * 64, n0 = (bb >> 5) * 64;
#pragma unroll
    for (int p = 0; p < 4; ++p) {
      int idx = t + p * 256;
      int r = idx >> 4, c4 = (idx & 15) * 4;
      *(float4*)&Ts[r][c4] = *(const float4*)(W + (size_t)(k0 + r) * H_ + n0 + c4);
    }
    __syncthreads();
#pragma unroll
    for (int p = 0; p < 4; ++p) {
      int idx = t + p * 256;
      int rr = idx >> 4, cc = (idx & 15) * 4;   // rr = n-local, cc = k-local
      unsigned short h[4], l[4];
#pragma unroll
      for (int q = 0; q < 4; ++q) {
        float f = Ts[cc + q][rr];
        h[q] = f2bf(f);
        l[q] = f2bf(f - bf2f(h[q]));
      }
      size_t o = (size_t)(n0 + rr) * H_ + k0 + cc;
      *(ushort4*)(Wth + o) = make_ushort4(h[0], h[1], h[2], h[3]);
      *(ushort4*)(Wtl + o) = make_ushort4(l[0], l[1], l[2], l[3]);
    }
  } else {
    const int bb = b - 17408;   // 1024 blocks * 256 threads * 16 B = 4 MiB
    ((float4*)G)[bb * 256 + t] = (float4){0.f, 0.f, 0.f, 0.f};
  }
}

// ------- 3-term split-bf16 MFMA GEMM, deep-pipelined (T3+T4+T5) -------
// Tile 256x128, BK=32, 512 threads (8 waves as 4x2, wave tile 64x64).
// Triple-buffered LDS (3 x 48 KiB = 144 KiB) -> depth-2 prefetch:
// while computing tile t, tile t+1 is resident, tile t+2's 6 glds are in
// flight -> end-of-tile wait is s_waitcnt vmcnt(6), NEVER vmcnt(0) in loop.
// Per-16-row-chunk XOR swizzle kept from previous version (0 bank conflicts).
// Grid (32,16) = 512 blocks = exactly 2 rounds / CU; bijective XCD remap:
// consecutive slots on an XCD share bm (A-panel L2 reuse).
#define TILE_USH 24576            // 48 KiB per tile in ushorts
#define OFF_AH 0                  // 256 rows x 32 ushorts
#define OFF_AL 8192
#define OFF_BH 16384              // 128 rows x 32 ushorts
#define OFF_BL 20480

__global__ __launch_bounds__(512, 2) void k_gemm3(
    const unsigned short* __restrict__ Ah, const unsigned short* __restrict__ Al,
    const unsigned short* __restrict__ Bh, const unsigned short* __restrict__ Bl,
    unsigned short* __restrict__ Eh, unsigned short* __restrict__ El) {
  __shared__ unsigned short lds[3 * TILE_USH];
  const int t = threadIdx.x;
  const int lane = t & 63, wid = t >> 6;     // 8 waves
  const int wm = wid >> 1, wn = wid & 1;     // 4x2 wave grid, wave tile 64x64
  const int l16 = lane & 15, quad = lane >> 4;

  // bijective XCD remap of the 512-block grid
  const int lin = blockIdx.x + (blockIdx.y << 5);
  const int xcd = lin & 7, slot = lin >> 3;
  const int bm = ((xcd >> 1) << 3) + (slot >> 3);   // 0..31
  const int bn = ((xcd & 1) << 3) + (slot & 7);     // 0..15

  // staging addresses (pre-swizzled global source, linear LDS dest)
  const int rl = lane >> 2;
  const int gg8 = (((lane & 3) ^ ((rl >> 1) & 3)) << 3);
  const unsigned short* gAh0 = Ah + (size_t)(bm * 256 + wid * 16 + rl) * H_ + gg8;
  const unsigned short* gAl0 = Al + (size_t)(bm * 256 + wid * 16 + rl) * H_ + gg8;
  const unsigned short* gAh1 = gAh0 + (size_t)128 * H_;
  const unsigned short* gAl1 = gAl0 + (size_t)128 * H_;
  const unsigned short* gBh  = Bh + (size_t)(bn * 128 + wid * 16 + rl) * H_ + gg8;
  const unsigned short* gBl  = Bl + (size_t)(bn * 128 + wid * 16 + rl) * H_ + gg8;
  const int dA0 = wid * 512;        // chunk wid   (16 rows * 32 ushorts)
  const int dA1 = dA0 + 4096;       // chunk wid+8
  const int dB  = wid * 512;

  // read-side swizzled fragment offsets
  const int colq = ((quad ^ ((l16 >> 1) & 3)) << 3);
  const int rA = (wm * 64 + l16) * 32 + colq;
  const int rB = (wn * 64 + l16) * 32 + colq;

  f32x4 acc[4][4];
#pragma unroll
  for (int i = 0; i < 4; ++i)
#pragma unroll
    for (int j = 0; j < 4; ++j) acc[i][j] = (f32x4)0.f;

  auto stage6 = [&](int bo, int k) {
    glds16(gAh0 + k, &lds[bo + OFF_AH + dA0]);
    glds16(gAh1 + k, &lds[bo + OFF_AH + dA1]);
    glds16(gAl0 + k, &lds[bo + OFF_AL + dA0]);
    glds16(gAl1 + k, &lds[bo + OFF_AL + dA1]);
    glds16(gBh + k,  &lds[bo + OFF_BH + dB]);
    glds16(gBl + k,  &lds[bo + OFF_BL + dB]);
  };

  // one K-tile: 2 phases, 24 MFMAs each; issue 3 prefetch glds per phase
  auto body = [&](int co, int n2o, int k2, bool issue) {
    bf16x8 ah[4], al[4], bh[4], bl[4];
    // ---- phase 0: n-frags 0,1 ----
    if (issue) {
      glds16(gAh0 + k2, &lds[n2o + OFF_AH + dA0]);
      glds16(gAl0 + k2, &lds[n2o + OFF_AL + dA0]);
      glds16(gBh + k2,  &lds[n2o + OFF_BH + dB]);
    }
#pragma unroll
    for (int i = 0; i < 4; ++i) {
      ah[i] = *(const bf16x8*)&lds[co + OFF_AH + rA + i * 512];
      al[i] = *(const bf16x8*)&lds[co + OFF_AL + rA + i * 512];
    }
#pragma unroll
    for (int j = 0; j < 2; ++j) {
      bh[j] = *(const bf16x8*)&lds[co + OFF_BH + rB + j * 512];
      bl[j] = *(const bf16x8*)&lds[co + OFF_BL + rB + j * 512];
    }
    __builtin_amdgcn_s_barrier();
    asm volatile("s_waitcnt lgkmcnt(0)" ::: "memory");
    __builtin_amdgcn_sched_barrier(0);
    __builtin_amdgcn_s_setprio(1);
#pragma unroll
    for (int i = 0; i < 4; ++i)
#pragma unroll
      for (int j = 0; j < 2; ++j) {
        acc[i][j] = __builtin_amdgcn_mfma_f32_16x16x32_bf16(ah[i], bh[j], acc[i][j], 0, 0, 0);
        acc[i][j] = __builtin_amdgcn_mfma_f32_16x16x32_bf16(ah[i], bl[j], acc[i][j], 0, 0, 0);
        acc[i][j] = __builtin_amdgcn_mfma_f32_16x16x32_bf16(al[i], bh[j], acc[i][j], 0, 0, 0);
      }
    __builtin_amdgcn_s_setprio(0);
    __builtin_amdgcn_s_barrier();
    // ---- phase 1: n-frags 2,3 ----
    if (issue) {
      glds16(gAh1 + k2, &lds[n2o + OFF_AH + dA1]);
      glds16(gAl1 + k2, &lds[n2o + OFF_AL + dA1]);
      glds16(gBl + k2,  &lds[n2o + OFF_BL + dB]);
    }
#pragma unroll
    for (int j = 2; j < 4; ++j) {
      bh[j] = *(const bf16x8*)&lds[co + OFF_BH + rB + j * 512];
      bl[j] = *(const bf16x8*)&lds[co + OFF_BL + rB + j * 512];
    }
    __builtin_amdgcn_s_barrier();
    asm volatile("s_waitcnt lgkmcnt(0)" ::: "memory");
    __builtin_amdgcn_sched_barrier(0);
    __builtin_amdgcn_s_setprio(1);
#pragma unroll
    for (int i = 0; i < 4; ++i)
#pragma unroll
      for (int j = 2; j < 4; ++j) {
        acc[i][j] = __builtin_amdgcn_mfma_f32_16x16x32_bf16(ah[i], bh[j], acc[i][j], 0, 0, 0);
        acc[i][j] = __builtin_amdgcn_mfma_f32_16x16x32_bf16(ah[i], bl[j], acc[i][j], 0, 0, 0);
        acc[i][j] = __builtin_amdgcn_mfma_f32_16x16x32_bf16(al[i], bh[j], acc[i][j], 0, 0, 0);
      }
    __builtin_amdgcn_s_setprio(0);
    // counted wait: tile t+1 landed, tile t+2's 6 loads stay in flight
    if (issue) asm volatile("s_waitcnt vmcnt(6)" ::: "memory");
    else       asm volatile("s_waitcnt vmcnt(0)" ::: "memory");
    __builtin_amdgcn_s_barrier();
  };

  // prologue: tiles 0 and 1 in flight, wait for tile 0 only
  stage6(0, 0);
  stage6(TILE_USH, 32);
  asm volatile("s_waitcnt vmcnt(6)" ::: "memory");
  __builtin_amdgcn_s_barrier();

  int cur = 0;
#pragma unroll 1
  for (int tt = 0; tt < 62; ++tt) {
    int n2 = cur + 2; if (n2 >= 3) n2 -= 3;
    body(cur * TILE_USH, n2 * TILE_USH, (tt + 2) * 32, true);
    cur = (cur == 2) ? 0 : cur + 1;
  }
  body(cur * TILE_USH, 0, 0, false);   // tile 62 (drains tile 63's loads)
  cur = (cur == 2) ? 0 : cur + 1;
  body(cur * TILE_USH, 0, 0, false);   // tile 63

  // epilogue: split-bf16 store of E
#pragma unroll
  for (int i = 0; i < 4; ++i) {
    const int row0 = bm * 256 + wm * 64 + i * 16 + quad * 4;
#pragma unroll
    for (int j = 0; j < 4; ++j) {
      const int col = bn * 128 + wn * 64 + j * 16 + l16;
#pragma unroll
      for (int r = 0; r < 4; ++r) {
        float v = acc[i][j][r];
        unsigned short hh = f2bf(v);
        unsigned short ll = f2bf(v - bf2f(hh));
        Eh[(size_t)(row0 + r) * H_ + col] = hh;
        El[(size_t)(row0 + r) * H_ + col] = ll;
      }
    }
  }
}

// ---- MFMA Gram: G[c] += Eh*Eh^T + Eh*El^T + El*Eh^T; each block does TWO
//      256-wide K chunks (register accumulate) -> atomics halved vs (8,64). ----
__global__ __launch_bounds__(256, 4) void k_gram_mfma(
    const unsigned short* __restrict__ Eh, const unsigned short* __restrict__ El,
    float* __restrict__ G) {
  __shared__ unsigned short sH[128 * 32], sL[128 * 32];
  const int t = threadIdx.x;
  const int kc = blockIdx.x;   // 0..3, each covers K chunks 2*kc, 2*kc+1
  const int cc = blockIdx.y;   // capsule
  const int lane = t & 63, wid = t >> 6;
  const int wm = wid >> 1, wn = wid & 1;
  const int l16 = lane & 15, quad = lane >> 4;

  const int rl = lane >> 2;
  const int gg = (lane & 3) ^ ((rl >> 1) & 3);
  const int c0 = wid * 2, c1 = c0 + 1;
  const unsigned short* gH0 = Eh + (size_t)(cc * 128 + c0 * 16 + rl) * H_ + gg * 8;
  const unsigned short* gH1 = Eh + (size_t)(cc * 128 + c1 * 16 + rl) * H_ + gg * 8;
  const unsigned short* gL0 = El + (size_t)(cc * 128 + c0 * 16 + rl) * H_ + gg * 8;
  const unsigned short* gL1 = El + (size_t)(cc * 128 + c1 * 16 + rl) * H_ + gg * 8;
  unsigned short* lH0 = sH + c0 * 512;
  unsigned short* lH1 = sH + c1 * 512;
  unsigned short* lL0 = sL + c0 * 512;
  unsigned short* lL1 = sL + c1 * 512;

  const int swz = ((l16 >> 1) & 3);
  const int colq = ((quad ^ swz) * 8);

  f32x4 acc[4][4];
#pragma unroll
  for (int i = 0; i < 4; ++i)
#pragma unroll
    for (int j = 0; j < 4; ++j) acc[i][j] = (f32x4)0.f;

  const int kbeg = kc * 512;           // two 256-wide chunks = 512
  for (int k0 = kbeg; k0 < kbeg + 512; k0 += 32) {
    __syncthreads();
    glds16(gH0 + k0, lH0);
    glds16(gH1 + k0, lH1);
    glds16(gL0 + k0, lL0);
    glds16(gL1 + k0, lL1);
    __syncthreads();

    bf16x8 ah[4], al[4], bh[4], bl[4];
#pragma unroll
    for (int i = 0; i < 4; ++i) {
      const int ra = (wm * 64 + i * 16 + l16) * 32;
      const int rb = (wn * 64 + i * 16 + l16) * 32;
      ah[i] = *(const bf16x8*)&sH[ra + colq];
      al[i] = *(const bf16x8*)&sL[ra + colq];
      bh[i] = *(const bf16x8*)&sH[rb + colq];
      bl[i] = *(const bf16x8*)&sL[rb + colq];
    }
#pragma unroll
    for (int i = 0; i < 4; ++i)
#pragma unroll
      for (int j = 0; j < 4; ++j) {
        acc[i][j] = __builtin_amdgcn_mfma_f32_16x16x32_bf16(ah[i], bh[j], acc[i][j], 0, 0, 0);
        acc[i][j] = __builtin_amdgcn_mfma_f32_16x16x32_bf16(ah[i], bl[j], acc[i][j], 0, 0, 0);
        acc[i][j] = __builtin_amdgcn_mfma_f32_16x16x32_bf16(al[i], bh[j], acc[i][j], 0, 0, 0);
      }
  }

  float* Gc = G + (size_t)cc * S_ * S_;
#pragma unroll
  for (int i = 0; i < 4; ++i) {
    const int row0 = wm * 64 + i * 16 + quad * 4;
#pragma unroll
    for (int j = 0; j < 4; ++j) {
      const int col = wn * 64 + j * 16 + l16;
#pragma unroll
      for (int r = 0; r < 4; ++r)
        atomicAdd(&Gc[(row0 + r) * S_ + col], acc[i][j][r]);
    }
  }
}

// ---- fused routing + projection: each block redoes its capsule's routing ----
__global__ void k_out2(const unsigned short* __restrict__ Eh,
                       const unsigned short* __restrict__ El,
                       const float* __restrict__ G, float* __restrict__ out) {
  const int c = blockIdx.y;
  const int s = threadIdx.x & 127;
  __shared__ float dsh[128];
  __shared__ float red[128];
  __shared__ float wsh[128];
  const float* Gc = G + (size_t)c * S_ * S_;
  float b = 0.f;
  for (int it = 0; it < 3; ++it) {
    red[s] = b; __syncthreads();
    for (int off = 64; off > 0; off >>= 1) {
      if (s < off) red[s] = fmaxf(red[s], red[s + off]);
      __syncthreads();
    }
    float mx = red[0]; __syncthreads();
    float ev = expf(b - mx);
    red[s] = ev; __syncthreads();
    for (int off = 64; off > 0; off >>= 1) {
      if (s < off) red[s] = red[s] + red[s + off];
      __syncthreads();
    }
    float Z = red[0]; __syncthreads();
    float d = ev / Z;
    dsh[s] = d; __syncthreads();
    float y = 0.f;   // (G d)_s via symmetric-column reads
#pragma unroll 8
    for (int j = 0; j < S_; ++j) y = fmaf(Gc[j * S_ + s], dsh[j], y);
    red[s] = d * y; __syncthreads();
    for (int off = 64; off > 0; off >>= 1) {
      if (s < off) red[s] = red[s] + red[s + off];
      __syncthreads();
    }
    float sq = red[0]; __syncthreads();
    float coeff = sq / (1.f + sq) / sqrtf(sq + 1e-9f);
    if (it == 2) wsh[s] = coeff * d;
    else b += coeff * y;
  }
  __syncthreads();

  // projection: out[c,h] = sum_s wsh[s] * (Eh+El)[c,s,h], 2 h per thread
  const int h2 = blockIdx.x * 256 + threadIdx.x;   // dword index, grid.x = 4
  const unsigned* Ph = (const unsigned*)(Eh + (size_t)c * S_ * H_) + h2;
  const unsigned* Pl = (const unsigned*)(El + (size_t)c * S_ * H_) + h2;
  float a0 = 0.f, a1 = 0.f;
#pragma unroll 8
  for (int ss = 0; ss < S_; ++ss) {
    unsigned uh = Ph[(size_t)ss * (H_ / 2)];
    unsigned ul = Pl[(size_t)ss * (H_ / 2)];
    a0 = fmaf(wsh[ss], bf2f((unsigned short)uh) + bf2f((unsigned short)ul), a0);
    a1 = fmaf(wsh[ss], bf2f((unsigned short)(uh >> 16)) + bf2f((unsigned short)(ul >> 16)), a1);
  }
  ((float2*)(out + (size_t)c * H_))[h2] = make_float2(a0, a1);
}

extern "C" void kernel_launch(void* const* d_in, const int* in_sizes, int n_in,
                              void* d_out, int out_size, void* d_ws, size_t ws_size,
                              hipStream_t stream) {
  (void)in_sizes; (void)n_in; (void)out_size; (void)ws_size;
  const float* x = (const float*)d_in[0];
  const float* W = (const float*)d_in[1];
  float* out = (float*)d_out;
  char* ws = (char*)d_ws;

  unsigned short* xh  = (unsigned short*)(ws);                 // 32 MiB
  unsigned short* xl  = (unsigned short*)(ws + 33554432);      // 32 MiB
  unsigned short* Wth = (unsigned short*)(ws + 67108864);      // 8 MiB
  unsigned short* Wtl = (unsigned short*)(ws + 75497472);      // 8 MiB
  unsigned short* Eh  = (unsigned short*)(ws + 83886080);      // 32 MiB
  unsigned short* El  = (unsigned short*)(ws + 117440512);     // 32 MiB
  float*          G   = (float*)(ws + 150994944);              // 4 MiB

  k_split_all<<<dim3(18432), 256, 0, stream>>>(x, xh, xl, W, Wth, Wtl, G);
  k_gemm3<<<dim3(32, 16), 512, 0, stream>>>(xh, xl, Wth, Wtl, Eh, El);
  k_gram_mfma<<<dim3(4, 64), 256, 0, stream>>>(Eh, El, G);
  k_out2<<<dim3(4, 64), 256, 0, stream>>>(Eh, El, G, out);
}

// Round 2
// 342.892 us; speedup vs baseline: 1.0866x; 1.0132x over previous
//
#include <hip/hip_runtime.h>

using bf16x8 = __attribute__((ext_vector_type(8))) __bf16;
using f32x4  = __attribute__((ext_vector_type(4))) float;

#define C_ 64
#define S_ 128
#define H_ 2048
#define M_ 8192

__device__ __forceinline__ unsigned short f2bf(float f) {
  unsigned u = __float_as_uint(f);
  u = u + 0x7fffu + ((u >> 16) & 1u);   // RNE
  return (unsigned short)(u >> 16);
}
__device__ __forceinline__ float bf2f(unsigned short h) {
  return __uint_as_float(((unsigned)h) << 16);
}

// async global->LDS, 16 B per lane; LDS dest = uniform base + lane*16
__device__ __forceinline__ void glds16(const unsigned short* g, unsigned short* l) {
  __builtin_amdgcn_global_load_lds(
      (const __attribute__((address_space(1))) void*)g,
      (__attribute__((address_space(3))) void*)l, 16, 0, 0);
}

// ---- fused: split x (blocks 0..16383) | split+transpose W (16384..17407) | zero G ----
__global__ void k_split_all(const float* __restrict__ x,
                            unsigned short* __restrict__ xh,
                            unsigned short* __restrict__ xl,
                            const float* __restrict__ W,
                            unsigned short* __restrict__ Wth,
                            unsigned short* __restrict__ Wtl,
                            float* __restrict__ G) {
  __shared__ float Ts[64][68];
  const int b = blockIdx.x;
  const int t = threadIdx.x;
  if (b < 16384) {
    int idx = b * 256 + t;
    float4 v = ((const float4*)x)[idx];
    float a[4] = {v.x, v.y, v.z, v.w};
    unsigned short h[4], l[4];
#pragma unroll
    for (int q = 0; q < 4; ++q) {
      h[q] = f2bf(a[q]);
      l[q] = f2bf(a[q] - bf2f(h[q]));
    }
    ((ushort4*)xh)[idx] = make_ushort4(h[0], h[1], h[2], h[3]);
    ((ushort4*)xl)[idx] = make_ushort4(l[0], l[1], l[2], l[3]);
  } else if (b < 17408) {
    const int bb = b - 16384;
    const int k0 = (bb & 31) * 64, n0 = (bb >> 5) * 64;
#pragma unroll
    for (int p = 0; p < 4; ++p) {
      int idx = t + p * 256;
      int r = idx >> 4, c4 = (idx & 15) * 4;
      *(float4*)&Ts[r][c4] = *(const float4*)(W + (size_t)(k0 + r) * H_ + n0 + c4);
    }
    __syncthreads();
#pragma unroll
    for (int p = 0; p < 4; ++p) {
      int idx = t + p * 256;
      int rr = idx >> 4, cc = (idx & 15) * 4;   // rr = n-local, cc = k-local
      unsigned short h[4], l[4];
#pragma unroll
      for (int q = 0; q < 4; ++q) {
        float f = Ts[cc + q][rr];
        h[q] = f2bf(f);
        l[q] = f2bf(f - bf2f(h[q]));
      }
      size_t o = (size_t)(n0 + rr) * H_ + k0 + cc;
      *(ushort4*)(Wth + o) = make_ushort4(h[0], h[1], h[2], h[3]);
      *(ushort4*)(Wtl + o) = make_ushort4(l[0], l[1], l[2], l[3]);
    }
  } else {
    const int bb = b - 17408;   // 1024 blocks * 256 threads * 16 B = 4 MiB
    ((float4*)G)[bb * 256 + t] = (float4){0.f, 0.f, 0.f, 0.f};
  }
}

// ------- 3-term split-bf16 MFMA GEMM, slip-pipelined (1 barrier / K-tile) -------
// Tile 256x128, BK=32, 512 threads (8 waves as 4x2, wave tile 64x64).
// Triple-buffered LDS (3 x 48 KiB): while computing tile t, tile t+1 is
// resident and tile t+2's 6 glds are in flight -> per-tile wait is
// s_waitcnt vmcnt(6) (counted, never 0 in the loop) + ONE s_barrier.
// No intra-tile barriers, no manual lgkmcnt: waves slip within a tile so
// wave i's MFMAs overlap wave j's ds_reads (LDS pipe 1536 cyc || matrix
// pipe 1862 cyc per tile per CU). Compiler emits fine-grained lgkmcnt
// between ds_read and dependent MFMA (m97 evidence).
#define TILE_USH 24576            // 48 KiB per tile in ushorts
#define OFF_AH 0                  // 256 rows x 32 ushorts
#define OFF_AL 8192
#define OFF_BH 16384              // 128 rows x 32 ushorts
#define OFF_BL 20480

__global__ __launch_bounds__(512, 2) void k_gemm3(
    const unsigned short* __restrict__ Ah, const unsigned short* __restrict__ Al,
    const unsigned short* __restrict__ Bh, const unsigned short* __restrict__ Bl,
    unsigned short* __restrict__ Eh, unsigned short* __restrict__ El) {
  __shared__ unsigned short lds[3 * TILE_USH];
  const int t = threadIdx.x;
  const int lane = t & 63, wid = t >> 6;     // 8 waves
  const int wm = wid >> 1, wn = wid & 1;     // 4x2 wave grid, wave tile 64x64
  const int l16 = lane & 15, quad = lane >> 4;

  // bijective XCD remap of the 512-block grid
  const int lin = blockIdx.x + (blockIdx.y << 5);
  const int xcd = lin & 7, slot = lin >> 3;
  const int bm = ((xcd >> 1) << 3) + (slot >> 3);   // 0..31
  const int bn = ((xcd & 1) << 3) + (slot & 7);     // 0..15

  // staging addresses (pre-swizzled global source, linear LDS dest)
  const int rl = lane >> 2;
  const int gg8 = (((lane & 3) ^ ((rl >> 1) & 3)) << 3);
  const unsigned short* gAh0 = Ah + (size_t)(bm * 256 + wid * 16 + rl) * H_ + gg8;
  const unsigned short* gAl0 = Al + (size_t)(bm * 256 + wid * 16 + rl) * H_ + gg8;
  const unsigned short* gAh1 = gAh0 + (size_t)128 * H_;
  const unsigned short* gAl1 = gAl0 + (size_t)128 * H_;
  const unsigned short* gBh  = Bh + (size_t)(bn * 128 + wid * 16 + rl) * H_ + gg8;
  const unsigned short* gBl  = Bl + (size_t)(bn * 128 + wid * 16 + rl) * H_ + gg8;
  const int dA0 = wid * 512;        // chunk wid   (16 rows * 32 ushorts)
  const int dA1 = dA0 + 4096;       // chunk wid+8
  const int dB  = wid * 512;

  // read-side swizzled fragment offsets
  const int colq = ((quad ^ ((l16 >> 1) & 3)) << 3);
  const int rA = (wm * 64 + l16) * 32 + colq;
  const int rB = (wn * 64 + l16) * 32 + colq;

  f32x4 acc[4][4];
#pragma unroll
  for (int i = 0; i < 4; ++i)
#pragma unroll
    for (int j = 0; j < 4; ++j) acc[i][j] = (f32x4)0.f;

  auto stage6 = [&](int bo, int k) {
    glds16(gAh0 + k, &lds[bo + OFF_AH + dA0]);
    glds16(gAh1 + k, &lds[bo + OFF_AH + dA1]);
    glds16(gAl0 + k, &lds[bo + OFF_AL + dA0]);
    glds16(gAl1 + k, &lds[bo + OFF_AL + dA1]);
    glds16(gBh + k,  &lds[bo + OFF_BH + dB]);
    glds16(gBl + k,  &lds[bo + OFF_BL + dB]);
  };

  // prologue: tiles 0 and 1 in flight, wait for tile 0 only
  stage6(0, 0);
  stage6(TILE_USH, 32);
  asm volatile("s_waitcnt vmcnt(6)" ::: "memory");
  __builtin_amdgcn_s_barrier();

  int cur = 0;
#pragma unroll 1
  for (int tt = 0; tt < 64; ++tt) {
    const int co = cur * TILE_USH;
    bf16x8 ah[4], al[4], bh[4], bl[4];
#pragma unroll
    for (int i = 0; i < 4; ++i) {
      ah[i] = *(const bf16x8*)&lds[co + OFF_AH + rA + i * 512];
      al[i] = *(const bf16x8*)&lds[co + OFF_AL + rA + i * 512];
      bh[i] = *(const bf16x8*)&lds[co + OFF_BH + rB + i * 512];
      bl[i] = *(const bf16x8*)&lds[co + OFF_BL + rB + i * 512];
    }
    if (tt < 62) {   // issue tile t+2 into the 3rd buffer
      int n2 = cur + 2; if (n2 >= 3) n2 -= 3;
      stage6(n2 * TILE_USH, (tt + 2) * 32);
    }
    __builtin_amdgcn_s_setprio(1);
#pragma unroll
    for (int i = 0; i < 4; ++i)
#pragma unroll
      for (int j = 0; j < 4; ++j) {
        acc[i][j] = __builtin_amdgcn_mfma_f32_16x16x32_bf16(ah[i], bh[j], acc[i][j], 0, 0, 0);
        acc[i][j] = __builtin_amdgcn_mfma_f32_16x16x32_bf16(ah[i], bl[j], acc[i][j], 0, 0, 0);
        acc[i][j] = __builtin_amdgcn_mfma_f32_16x16x32_bf16(al[i], bh[j], acc[i][j], 0, 0, 0);
      }
    __builtin_amdgcn_s_setprio(0);
    // counted wait: tile t+1 has landed; tile t+2's 6 loads stay in flight
    if (tt < 62)       asm volatile("s_waitcnt vmcnt(6)" ::: "memory");
    else if (tt == 62) asm volatile("s_waitcnt vmcnt(0)" ::: "memory");
    if (tt < 63) __builtin_amdgcn_s_barrier();
    cur = cur + 1; if (cur == 3) cur = 0;
  }

  // epilogue: split-bf16 store of E
#pragma unroll
  for (int i = 0; i < 4; ++i) {
    const int row0 = bm * 256 + wm * 64 + i * 16 + quad * 4;
#pragma unroll
    for (int j = 0; j < 4; ++j) {
      const int col = bn * 128 + wn * 64 + j * 16 + l16;
#pragma unroll
      for (int r = 0; r < 4; ++r) {
        float v = acc[i][j][r];
        unsigned short hh = f2bf(v);
        unsigned short ll = f2bf(v - bf2f(hh));
        Eh[(size_t)(row0 + r) * H_ + col] = hh;
        El[(size_t)(row0 + r) * H_ + col] = ll;
      }
    }
  }
}

// ---- MFMA Gram: G[c] += Eh*Eh^T + Eh*El^T + El*Eh^T; each block does TWO
//      256-wide K chunks (register accumulate) -> atomics halved vs (8,64). ----
__global__ __launch_bounds__(256, 4) void k_gram_mfma(
    const unsigned short* __restrict__ Eh, const unsigned short* __restrict__ El,
    float* __restrict__ G) {
  __shared__ unsigned short sH[128 * 32], sL[128 * 32];
  const int t = threadIdx.x;
  const int kc = blockIdx.x;   // 0..3, each covers K chunks 2*kc, 2*kc+1
  const int cc = blockIdx.y;   // capsule
  const int lane = t & 63, wid = t >> 6;
  const int wm = wid >> 1, wn = wid & 1;
  const int l16 = lane & 15, quad = lane >> 4;

  const int rl = lane >> 2;
  const int gg = (lane & 3) ^ ((rl >> 1) & 3);
  const int c0 = wid * 2, c1 = c0 + 1;
  const unsigned short* gH0 = Eh + (size_t)(cc * 128 + c0 * 16 + rl) * H_ + gg * 8;
  const unsigned short* gH1 = Eh + (size_t)(cc * 128 + c1 * 16 + rl) * H_ + gg * 8;
  const unsigned short* gL0 = El + (size_t)(cc * 128 + c0 * 16 + rl) * H_ + gg * 8;
  const unsigned short* gL1 = El + (size_t)(cc * 128 + c1 * 16 + rl) * H_ + gg * 8;
  unsigned short* lH0 = sH + c0 * 512;
  unsigned short* lH1 = sH + c1 * 512;
  unsigned short* lL0 = sL + c0 * 512;
  unsigned short* lL1 = sL + c1 * 512;

  const int swz = ((l16 >> 1) & 3);
  const int colq = ((quad ^ swz) * 8);

  f32x4 acc[4][4];
#pragma unroll
  for (int i = 0; i < 4; ++i)
#pragma unroll
    for (int j = 0; j < 4; ++j) acc[i][j] = (f32x4)0.f;

  const int kbeg = kc * 512;           // two 256-wide chunks = 512
  for (int k0 = kbeg; k0 < kbeg + 512; k0 += 32) {
    __syncthreads();
    glds16(gH0 + k0, lH0);
    glds16(gH1 + k0, lH1);
    glds16(gL0 + k0, lL0);
    glds16(gL1 + k0, lL1);
    __syncthreads();

    bf16x8 ah[4], al[4], bh[4], bl[4];
#pragma unroll
    for (int i = 0; i < 4; ++i) {
      const int ra = (wm * 64 + i * 16 + l16) * 32;
      const int rb = (wn * 64 + i * 16 + l16) * 32;
      ah[i] = *(const bf16x8*)&sH[ra + colq];
      al[i] = *(const bf16x8*)&sL[ra + colq];
      bh[i] = *(const bf16x8*)&sH[rb + colq];
      bl[i] = *(const bf16x8*)&sL[rb + colq];
    }
#pragma unroll
    for (int i = 0; i < 4; ++i)
#pragma unroll
      for (int j = 0; j < 4; ++j) {
        acc[i][j] = __builtin_amdgcn_mfma_f32_16x16x32_bf16(ah[i], bh[j], acc[i][j], 0, 0, 0);
        acc[i][j] = __builtin_amdgcn_mfma_f32_16x16x32_bf16(ah[i], bl[j], acc[i][j], 0, 0, 0);
        acc[i][j] = __builtin_amdgcn_mfma_f32_16x16x32_bf16(al[i], bh[j], acc[i][j], 0, 0, 0);
      }
  }

  float* Gc = G + (size_t)cc * S_ * S_;
#pragma unroll
  for (int i = 0; i < 4; ++i) {
    const int row0 = wm * 64 + i * 16 + quad * 4;
#pragma unroll
    for (int j = 0; j < 4; ++j) {
      const int col = wn * 64 + j * 16 + l16;
#pragma unroll
      for (int r = 0; r < 4; ++r)
        atomicAdd(&Gc[(row0 + r) * S_ + col], acc[i][j][r]);
    }
  }
}

// ---- fused routing + projection: each block redoes its capsule's routing ----
__global__ void k_out2(const unsigned short* __restrict__ Eh,
                       const unsigned short* __restrict__ El,
                       const float* __restrict__ G, float* __restrict__ out) {
  const int c = blockIdx.y;
  const int s = threadIdx.x & 127;
  __shared__ float dsh[128];
  __shared__ float red[128];
  __shared__ float wsh[128];
  const float* Gc = G + (size_t)c * S_ * S_;
  float b = 0.f;
  for (int it = 0; it < 3; ++it) {
    red[s] = b; __syncthreads();
    for (int off = 64; off > 0; off >>= 1) {
      if (s < off) red[s] = fmaxf(red[s], red[s + off]);
      __syncthreads();
    }
    float mx = red[0]; __syncthreads();
    float ev = expf(b - mx);
    red[s] = ev; __syncthreads();
    for (int off = 64; off > 0; off >>= 1) {
      if (s < off) red[s] = red[s] + red[s + off];
      __syncthreads();
    }
    float Z = red[0]; __syncthreads();
    float d = ev / Z;
    dsh[s] = d; __syncthreads();
    float y = 0.f;   // (G d)_s via symmetric-column reads
#pragma unroll 8
    for (int j = 0; j < S_; ++j) y = fmaf(Gc[j * S_ + s], dsh[j], y);
    red[s] = d * y; __syncthreads();
    for (int off = 64; off > 0; off >>= 1) {
      if (s < off) red[s] = red[s] + red[s + off];
      __syncthreads();
    }
    float sq = red[0]; __syncthreads();
    float coeff = sq / (1.f + sq) / sqrtf(sq + 1e-9f);
    if (it == 2) wsh[s] = coeff * d;
    else b += coeff * y;
  }
  __syncthreads();

  // projection: out[c,h] = sum_s wsh[s] * (Eh+El)[c,s,h], 2 h per thread
  const int h2 = blockIdx.x * 256 + threadIdx.x;   // dword index, grid.x = 4
  const unsigned* Ph = (const unsigned*)(Eh + (size_t)c * S_ * H_) + h2;
  const unsigned* Pl = (const unsigned*)(El + (size_t)c * S_ * H_) + h2;
  float a0 = 0.f, a1 = 0.f;
#pragma unroll 8
  for (int ss = 0; ss < S_; ++ss) {
    unsigned uh = Ph[(size_t)ss * (H_ / 2)];
    unsigned ul = Pl[(size_t)ss * (H_ / 2)];
    a0 = fmaf(wsh[ss], bf2f((unsigned short)uh) + bf2f((unsigned short)ul), a0);
    a1 = fmaf(wsh[ss], bf2f((unsigned short)(uh >> 16)) + bf2f((unsigned short)(ul >> 16)), a1);
  }
  ((float2*)(out + (size_t)c * H_))[h2] = make_float2(a0, a1);
}

extern "C" void kernel_launch(void* const* d_in, const int* in_sizes, int n_in,
                              void* d_out, int out_size, void* d_ws, size_t ws_size,
                              hipStream_t stream) {
  (void)in_sizes; (void)n_in; (void)out_size; (void)ws_size;
  const float* x = (const float*)d_in[0];
  const float* W = (const float*)d_in[1];
  float* out = (float*)d_out;
  char* ws = (char*)d_ws;

  unsigned short* xh  = (unsigned short*)(ws);                 // 32 MiB
  unsigned short* xl  = (unsigned short*)(ws + 33554432);      // 32 MiB
  unsigned short* Wth = (unsigned short*)(ws + 67108864);      // 8 MiB
  unsigned short* Wtl = (unsigned short*)(ws + 75497472);      // 8 MiB
  unsigned short* Eh  = (unsigned short*)(ws + 83886080);      // 32 MiB
  unsigned short* El  = (unsigned short*)(ws + 117440512);     // 32 MiB
  float*          G   = (float*)(ws + 150994944);              // 4 MiB

  k_split_all<<<dim3(18432), 256, 0, stream>>>(x, xh, xl, W, Wth, Wtl, G);
  k_gemm3<<<dim3(32, 16), 512, 0, stream>>>(xh, xl, Wth, Wtl, Eh, El);
  k_gram_mfma<<<dim3(4, 64), 256, 0, stream>>>(Eh, El, G);
  k_out2<<<dim3(4, 64), 256, 0, stream>>>(Eh, El, G, out);
}

// Round 3
// 339.939 us; speedup vs baseline: 1.0960x; 1.0087x over previous
//
#include <hip/hip_runtime.h>

using bf16x8 = __attribute__((ext_vector_type(8))) __bf16;
using f32x4  = __attribute__((ext_vector_type(4))) float;

#define C_ 64
#define S_ 128
#define H_ 2048
#define M_ 8192

__device__ __forceinline__ unsigned short f2bf(float f) {
  unsigned u = __float_as_uint(f);
  u = u + 0x7fffu + ((u >> 16) & 1u);   // RNE
  return (unsigned short)(u >> 16);
}
__device__ __forceinline__ float bf2f(unsigned short h) {
  return __uint_as_float(((unsigned)h) << 16);
}

// async global->LDS, 16 B per lane; LDS dest = uniform base + lane*16
__device__ __forceinline__ void glds16(const unsigned short* g, unsigned short* l) {
  __builtin_amdgcn_global_load_lds(
      (const __attribute__((address_space(1))) void*)g,
      (__attribute__((address_space(3))) void*)l, 16, 0, 0);
}

// ---- fused: split x (blocks 0..16383) | split+transpose W (16384..17407) | zero G ----
__global__ void k_split_all(const float* __restrict__ x,
                            unsigned short* __restrict__ xh,
                            unsigned short* __restrict__ xl,
                            const float* __restrict__ W,
                            unsigned short* __restrict__ Wth,
                            unsigned short* __restrict__ Wtl,
                            float* __restrict__ G) {
  __shared__ float Ts[64][68];
  const int b = blockIdx.x;
  const int t = threadIdx.x;
  if (b < 16384) {
    int idx = b * 256 + t;
    float4 v = ((const float4*)x)[idx];
    float a[4] = {v.x, v.y, v.z, v.w};
    unsigned short h[4], l[4];
#pragma unroll
    for (int q = 0; q < 4; ++q) {
      h[q] = f2bf(a[q]);
      l[q] = f2bf(a[q] - bf2f(h[q]));
    }
    ((ushort4*)xh)[idx] = make_ushort4(h[0], h[1], h[2], h[3]);
    ((ushort4*)xl)[idx] = make_ushort4(l[0], l[1], l[2], l[3]);
  } else if (b < 17408) {
    const int bb = b - 16384;
    const int k0 = (bb & 31) * 64, n0 = (bb >> 5) * 64;
#pragma unroll
    for (int p = 0; p < 4; ++p) {
      int idx = t + p * 256;
      int r = idx >> 4, c4 = (idx & 15) * 4;
      *(float4*)&Ts[r][c4] = *(const float4*)(W + (size_t)(k0 + r) * H_ + n0 + c4);
    }
    __syncthreads();
#pragma unroll
    for (int p = 0; p < 4; ++p) {
      int idx = t + p * 256;
      int rr = idx >> 4, cc = (idx & 15) * 4;   // rr = n-local, cc = k-local
      unsigned short h[4], l[4];
#pragma unroll
      for (int q = 0; q < 4; ++q) {
        float f = Ts[cc + q][rr];
        h[q] = f2bf(f);
        l[q] = f2bf(f - bf2f(h[q]));
      }
      size_t o = (size_t)(n0 + rr) * H_ + k0 + cc;
      *(ushort4*)(Wth + o) = make_ushort4(h[0], h[1], h[2], h[3]);
      *(ushort4*)(Wtl + o) = make_ushort4(l[0], l[1], l[2], l[3]);
    }
  } else {
    const int bb = b - 17408;   // 1024 blocks * 256 threads * 16 B = 4 MiB
    ((float4*)G)[bb * 256 + t] = (float4){0.f, 0.f, 0.f, 0.f};
  }
}

// ------- 3-term split-bf16 MFMA GEMM, reg-double-buffered pipeline -------
// Tile 256x128, BK=32, 512 threads (8 waves as 4x2, wave tile 64x64).
// LDS: 3 x 48 KiB buffers, counted vmcnt(6) (tile t+2 in flight across the
// barrier). NEW (R3): TWO register fragment sets. At tile t the operands are
// already in regs; the wave issues tile t+1's 16 ds_read_b128 (buffer already
// landed: vmcnt(6)+barrier this tile) then immediately the 48 MFMAs of tile
// t -- no dependency, so the LDS pipe drains reads UNDER the MFMA burst
// within each wave. lgkmcnt(0) is folded into the pre-barrier wait (WAR vs
// the LDS-DMA), sched_barrier(0) pins the reads below the barrier.
#define TILE_USH 24576            // 48 KiB per tile in ushorts
#define OFF_AH 0                  // 256 rows x 32 ushorts
#define OFF_AL 8192
#define OFF_BH 16384              // 128 rows x 32 ushorts
#define OFF_BL 20480

#define LOADSET(AH, AL, BH, BL, off)                                  \
  do {                                                                \
    const int _o = (off);                                             \
    _Pragma("unroll") for (int i = 0; i < 4; ++i) {                   \
      AH[i] = *(const bf16x8*)&lds[_o + OFF_AH + rA + i * 512];       \
      AL[i] = *(const bf16x8*)&lds[_o + OFF_AL + rA + i * 512];       \
      BH[i] = *(const bf16x8*)&lds[_o + OFF_BH + rB + i * 512];       \
      BL[i] = *(const bf16x8*)&lds[_o + OFF_BL + rB + i * 512];       \
    }                                                                 \
  } while (0)

#define MFMASET(AH, AL, BH, BL)                                                                  \
  do {                                                                                           \
    __builtin_amdgcn_s_setprio(1);                                                               \
    _Pragma("unroll") for (int i = 0; i < 4; ++i)                                                \
        _Pragma("unroll") for (int j = 0; j < 4; ++j) {                                          \
      acc[i][j] = __builtin_amdgcn_mfma_f32_16x16x32_bf16(AH[i], BH[j], acc[i][j], 0, 0, 0);     \
      acc[i][j] = __builtin_amdgcn_mfma_f32_16x16x32_bf16(AH[i], BL[j], acc[i][j], 0, 0, 0);     \
      acc[i][j] = __builtin_amdgcn_mfma_f32_16x16x32_bf16(AL[i], BH[j], acc[i][j], 0, 0, 0);     \
    }                                                                                            \
    __builtin_amdgcn_s_setprio(0);                                                               \
  } while (0)

__global__ __launch_bounds__(512, 2) void k_gemm3(
    const unsigned short* __restrict__ Ah, const unsigned short* __restrict__ Al,
    const unsigned short* __restrict__ Bh, const unsigned short* __restrict__ Bl,
    unsigned short* __restrict__ Eh, unsigned short* __restrict__ El) {
  __shared__ unsigned short lds[3 * TILE_USH];
  const int t = threadIdx.x;
  const int lane = t & 63, wid = t >> 6;     // 8 waves
  const int wm = wid >> 1, wn = wid & 1;     // 4x2 wave grid, wave tile 64x64
  const int l16 = lane & 15, quad = lane >> 4;

  // bijective XCD remap of the 512-block grid
  const int lin = blockIdx.x + (blockIdx.y << 5);
  const int xcd = lin & 7, slot = lin >> 3;
  const int bm = ((xcd >> 1) << 3) + (slot >> 3);   // 0..31
  const int bn = ((xcd & 1) << 3) + (slot & 7);     // 0..15

  // staging addresses (pre-swizzled global source, linear LDS dest)
  const int rl = lane >> 2;
  const int gg8 = (((lane & 3) ^ ((rl >> 1) & 3)) << 3);
  const unsigned short* gAh0 = Ah + (size_t)(bm * 256 + wid * 16 + rl) * H_ + gg8;
  const unsigned short* gAl0 = Al + (size_t)(bm * 256 + wid * 16 + rl) * H_ + gg8;
  const unsigned short* gAh1 = gAh0 + (size_t)128 * H_;
  const unsigned short* gAl1 = gAl0 + (size_t)128 * H_;
  const unsigned short* gBh  = Bh + (size_t)(bn * 128 + wid * 16 + rl) * H_ + gg8;
  const unsigned short* gBl  = Bl + (size_t)(bn * 128 + wid * 16 + rl) * H_ + gg8;
  const int dA0 = wid * 512;        // chunk = 16 rows * 32 ushorts = 1 KiB
  const int dA1 = dA0 + 4096;       // chunk wid+8
  const int dB  = wid * 512;

  // read-side swizzled fragment offsets
  const int colq = ((quad ^ ((l16 >> 1) & 3)) << 3);
  const int rA = (wm * 64 + l16) * 32 + colq;
  const int rB = (wn * 64 + l16) * 32 + colq;

  f32x4 acc[4][4];
#pragma unroll
  for (int i = 0; i < 4; ++i)
#pragma unroll
    for (int j = 0; j < 4; ++j) acc[i][j] = (f32x4)0.f;

  auto stage6 = [&](int bo, int k) {
    glds16(gAh0 + k, &lds[bo + OFF_AH + dA0]);
    glds16(gAh1 + k, &lds[bo + OFF_AH + dA1]);
    glds16(gAl0 + k, &lds[bo + OFF_AL + dA0]);
    glds16(gAl1 + k, &lds[bo + OFF_AL + dA1]);
    glds16(gBh + k,  &lds[bo + OFF_BH + dB]);
    glds16(gBl + k,  &lds[bo + OFF_BL + dB]);
  };

  // prologue: tiles 0,1 in flight; wait tile 0; load its fragments to regs
  stage6(0, 0);
  stage6(TILE_USH, 32);
  asm volatile("s_waitcnt vmcnt(6)" ::: "memory");
  __builtin_amdgcn_s_barrier();
  __builtin_amdgcn_sched_barrier(0);

  bf16x8 ahA[4], alA[4], bhA[4], blA[4];
  bf16x8 ahB[4], alB[4], bhB[4], blB[4];
  LOADSET(ahA, alA, bhA, blA, 0);

  int stage_off = 2 * TILE_USH;   // buffer of tile tt+2 at iter tt
  int read_off  = TILE_USH;       // buffer of tile tt+1 at iter tt

#pragma unroll 1
  for (int tt = 0; tt < 62; tt += 2) {
    // ---- tile tt: prefetch B-set (tile tt+1), compute A-set ----
    stage6(stage_off, (tt + 2) * 32);
    stage_off += TILE_USH; if (stage_off == 3 * TILE_USH) stage_off = 0;
    asm volatile("s_waitcnt vmcnt(6) lgkmcnt(0)" ::: "memory");
    __builtin_amdgcn_s_barrier();
    __builtin_amdgcn_sched_barrier(0);
    LOADSET(ahB, alB, bhB, blB, read_off);
    read_off += TILE_USH; if (read_off == 3 * TILE_USH) read_off = 0;
    MFMASET(ahA, alA, bhA, blA);
    // ---- tile tt+1: prefetch A-set (tile tt+2), compute B-set ----
    stage6(stage_off, (tt + 3) * 32);
    stage_off += TILE_USH; if (stage_off == 3 * TILE_USH) stage_off = 0;
    asm volatile("s_waitcnt vmcnt(6) lgkmcnt(0)" ::: "memory");
    __builtin_amdgcn_s_barrier();
    __builtin_amdgcn_sched_barrier(0);
    LOADSET(ahA, alA, bhA, blA, read_off);
    read_off += TILE_USH; if (read_off == 3 * TILE_USH) read_off = 0;
    MFMASET(ahB, alB, bhB, blB);
  }

  // tile 62: all loads drained, load tile 63's fragments, compute A-set
  asm volatile("s_waitcnt vmcnt(0) lgkmcnt(0)" ::: "memory");
  __builtin_amdgcn_s_barrier();
  __builtin_amdgcn_sched_barrier(0);
  LOADSET(ahB, alB, bhB, blB, read_off);
  MFMASET(ahA, alA, bhA, blA);
  // tile 63: compute B-set (no loads, no barrier)
  MFMASET(ahB, alB, bhB, blB);

  // epilogue: split-bf16 store of E
#pragma unroll
  for (int i = 0; i < 4; ++i) {
    const int row0 = bm * 256 + wm * 64 + i * 16 + quad * 4;
#pragma unroll
    for (int j = 0; j < 4; ++j) {
      const int col = bn * 128 + wn * 64 + j * 16 + l16;
#pragma unroll
      for (int r = 0; r < 4; ++r) {
        float v = acc[i][j][r];
        unsigned short hh = f2bf(v);
        unsigned short ll = f2bf(v - bf2f(hh));
        Eh[(size_t)(row0 + r) * H_ + col] = hh;
        El[(size_t)(row0 + r) * H_ + col] = ll;
      }
    }
  }
}

// ---- MFMA Gram: G[c] += Eh*Eh^T + Eh*El^T + El*Eh^T; each block does TWO
//      256-wide K chunks (register accumulate) -> atomics halved vs (8,64). ----
__global__ __launch_bounds__(256, 4) void k_gram_mfma(
    const unsigned short* __restrict__ Eh, const unsigned short* __restrict__ El,
    float* __restrict__ G) {
  __shared__ unsigned short sH[128 * 32], sL[128 * 32];
  const int t = threadIdx.x;
  const int kc = blockIdx.x;   // 0..3, each covers K chunks 2*kc, 2*kc+1
  const int cc = blockIdx.y;   // capsule
  const int lane = t & 63, wid = t >> 6;
  const int wm = wid >> 1, wn = wid & 1;
  const int l16 = lane & 15, quad = lane >> 4;

  const int rl = lane >> 2;
  const int gg = (lane & 3) ^ ((rl >> 1) & 3);
  const int c0 = wid * 2, c1 = c0 + 1;
  const unsigned short* gH0 = Eh + (size_t)(cc * 128 + c0 * 16 + rl) * H_ + gg * 8;
  const unsigned short* gH1 = Eh + (size_t)(cc * 128 + c1 * 16 + rl) * H_ + gg * 8;
  const unsigned short* gL0 = El + (size_t)(cc * 128 + c0 * 16 + rl) * H_ + gg * 8;
  const unsigned short* gL1 = El + (size_t)(cc * 128 + c1 * 16 + rl) * H_ + gg * 8;
  unsigned short* lH0 = sH + c0 * 512;
  unsigned short* lH1 = sH + c1 * 512;
  unsigned short* lL0 = sL + c0 * 512;
  unsigned short* lL1 = sL + c1 * 512;

  const int swz = ((l16 >> 1) & 3);
  const int colq = ((quad ^ swz) * 8);

  f32x4 acc[4][4];
#pragma unroll
  for (int i = 0; i < 4; ++i)
#pragma unroll
    for (int j = 0; j < 4; ++j) acc[i][j] = (f32x4)0.f;

  const int kbeg = kc * 512;           // two 256-wide chunks = 512
  for (int k0 = kbeg; k0 < kbeg + 512; k0 += 32) {
    __syncthreads();
    glds16(gH0 + k0, lH0);
    glds16(gH1 + k0, lH1);
    glds16(gL0 + k0, lL0);
    glds16(gL1 + k0, lL1);
    __syncthreads();

    bf16x8 ah[4], al[4], bh[4], bl[4];
#pragma unroll
    for (int i = 0; i < 4; ++i) {
      const int ra = (wm * 64 + i * 16 + l16) * 32;
      const int rb = (wn * 64 + i * 16 + l16) * 32;
      ah[i] = *(const bf16x8*)&sH[ra + colq];
      al[i] = *(const bf16x8*)&sL[ra + colq];
      bh[i] = *(const bf16x8*)&sH[rb + colq];
      bl[i] = *(const bf16x8*)&sL[rb + colq];
    }
#pragma unroll
    for (int i = 0; i < 4; ++i)
#pragma unroll
      for (int j = 0; j < 4; ++j) {
        acc[i][j] = __builtin_amdgcn_mfma_f32_16x16x32_bf16(ah[i], bh[j], acc[i][j], 0, 0, 0);
        acc[i][j] = __builtin_amdgcn_mfma_f32_16x16x32_bf16(ah[i], bl[j], acc[i][j], 0, 0, 0);
        acc[i][j] = __builtin_amdgcn_mfma_f32_16x16x32_bf16(al[i], bh[j], acc[i][j], 0, 0, 0);
      }
  }

  float* Gc = G + (size_t)cc * S_ * S_;
#pragma unroll
  for (int i = 0; i < 4; ++i) {
    const int row0 = wm * 64 + i * 16 + quad * 4;
#pragma unroll
    for (int j = 0; j < 4; ++j) {
      const int col = wn * 64 + j * 16 + l16;
#pragma unroll
      for (int r = 0; r < 4; ++r)
        atomicAdd(&Gc[(row0 + r) * S_ + col], acc[i][j][r]);
    }
  }
}

// ---- fused routing + projection: each block redoes its capsule's routing ----
__global__ void k_out2(const unsigned short* __restrict__ Eh,
                       const unsigned short* __restrict__ El,
                       const float* __restrict__ G, float* __restrict__ out) {
  const int c = blockIdx.y;
  const int s = threadIdx.x & 127;
  __shared__ float dsh[128];
  __shared__ float red[128];
  __shared__ float wsh[128];
  const float* Gc = G + (size_t)c * S_ * S_;
  float b = 0.f;
  for (int it = 0; it < 3; ++it) {
    red[s] = b; __syncthreads();
    for (int off = 64; off > 0; off >>= 1) {
      if (s < off) red[s] = fmaxf(red[s], red[s + off]);
      __syncthreads();
    }
    float mx = red[0]; __syncthreads();
    float ev = expf(b - mx);
    red[s] = ev; __syncthreads();
    for (int off = 64; off > 0; off >>= 1) {
      if (s < off) red[s] = red[s] + red[s + off];
      __syncthreads();
    }
    float Z = red[0]; __syncthreads();
    float d = ev / Z;
    dsh[s] = d; __syncthreads();
    float y = 0.f;   // (G d)_s via symmetric-column reads
#pragma unroll 8
    for (int j = 0; j < S_; ++j) y = fmaf(Gc[j * S_ + s], dsh[j], y);
    red[s] = d * y; __syncthreads();
    for (int off = 64; off > 0; off >>= 1) {
      if (s < off) red[s] = red[s] + red[s + off];
      __syncthreads();
    }
    float sq = red[0]; __syncthreads();
    float coeff = sq / (1.f + sq) / sqrtf(sq + 1e-9f);
    if (it == 2) wsh[s] = coeff * d;
    else b += coeff * y;
  }
  __syncthreads();

  // projection: out[c,h] = sum_s wsh[s] * (Eh+El)[c,s,h], 2 h per thread
  const int h2 = blockIdx.x * 256 + threadIdx.x;   // dword index, grid.x = 4
  const unsigned* Ph = (const unsigned*)(Eh + (size_t)c * S_ * H_) + h2;
  const unsigned* Pl = (const unsigned*)(El + (size_t)c * S_ * H_) + h2;
  float a0 = 0.f, a1 = 0.f;
#pragma unroll 8
  for (int ss = 0; ss < S_; ++ss) {
    unsigned uh = Ph[(size_t)ss * (H_ / 2)];
    unsigned ul = Pl[(size_t)ss * (H_ / 2)];
    a0 = fmaf(wsh[ss], bf2f((unsigned short)uh) + bf2f((unsigned short)ul), a0);
    a1 = fmaf(wsh[ss], bf2f((unsigned short)(uh >> 16)) + bf2f((unsigned short)(ul >> 16)), a1);
  }
  ((float2*)(out + (size_t)c * H_))[h2] = make_float2(a0, a1);
}

extern "C" void kernel_launch(void* const* d_in, const int* in_sizes, int n_in,
                              void* d_out, int out_size, void* d_ws, size_t ws_size,
                              hipStream_t stream) {
  (void)in_sizes; (void)n_in; (void)out_size; (void)ws_size;
  const float* x = (const float*)d_in[0];
  const float* W = (const float*)d_in[1];
  float* out = (float*)d_out;
  char* ws = (char*)d_ws;

  unsigned short* xh  = (unsigned short*)(ws);                 // 32 MiB
  unsigned short* xl  = (unsigned short*)(ws + 33554432);      // 32 MiB
  unsigned short* Wth = (unsigned short*)(ws + 67108864);      // 8 MiB
  unsigned short* Wtl = (unsigned short*)(ws + 75497472);      // 8 MiB
  unsigned short* Eh  = (unsigned short*)(ws + 83886080);      // 32 MiB
  unsigned short* El  = (unsigned short*)(ws + 117440512);     // 32 MiB
  float*          G   = (float*)(ws + 150994944);              // 4 MiB

  k_split_all<<<dim3(18432), 256, 0, stream>>>(x, xh, xl, W, Wth, Wtl, G);
  k_gemm3<<<dim3(32, 16), 512, 0, stream>>>(xh, xl, Wth, Wtl, Eh, El);
  k_gram_mfma<<<dim3(4, 64), 256, 0, stream>>>(Eh, El, G);
  k_out2<<<dim3(4, 64), 256, 0, stream>>>(Eh, El, G, out);
}

// Round 4
// 338.110 us; speedup vs baseline: 1.1020x; 1.0054x over previous
//
#include <hip/hip_runtime.h>

using bf16x8 = __attribute__((ext_vector_type(8))) __bf16;
using f32x4  = __attribute__((ext_vector_type(4))) float;

#define C_ 64
#define S_ 128
#define H_ 2048
#define M_ 8192

__device__ __forceinline__ unsigned short f2bf(float f) {
  unsigned u = __float_as_uint(f);
  u = u + 0x7fffu + ((u >> 16) & 1u);   // RNE
  return (unsigned short)(u >> 16);
}
__device__ __forceinline__ float bf2f(unsigned short h) {
  return __uint_as_float(((unsigned)h) << 16);
}

// async global->LDS, 16 B per lane; LDS dest = uniform base + lane*16
__device__ __forceinline__ void glds16(const unsigned short* g, unsigned short* l) {
  __builtin_amdgcn_global_load_lds(
      (const __attribute__((address_space(1))) void*)g,
      (__attribute__((address_space(3))) void*)l, 16, 0, 0);
}

// ---- fused: split x (blocks 0..16383) | split+transpose W (16384..17407) | zero G ----
__global__ void k_split_all(const float* __restrict__ x,
                            unsigned short* __restrict__ xh,
                            unsigned short* __restrict__ xl,
                            const float* __restrict__ W,
                            unsigned short* __restrict__ Wth,
                            unsigned short* __restrict__ Wtl,
                            float* __restrict__ G) {
  __shared__ float Ts[64][68];
  const int b = blockIdx.x;
  const int t = threadIdx.x;
  if (b < 16384) {
    int idx = b * 256 + t;
    float4 v = ((const float4*)x)[idx];
    float a[4] = {v.x, v.y, v.z, v.w};
    unsigned short h[4], l[4];
#pragma unroll
    for (int q = 0; q < 4; ++q) {
      h[q] = f2bf(a[q]);
      l[q] = f2bf(a[q] - bf2f(h[q]));
    }
    ((ushort4*)xh)[idx] = make_ushort4(h[0], h[1], h[2], h[3]);
    ((ushort4*)xl)[idx] = make_ushort4(l[0], l[1], l[2], l[3]);
  } else if (b < 17408) {
    const int bb = b - 16384;
    const int k0 = (bb & 31) * 64, n0 = (bb >> 5) * 64;
#pragma unroll
    for (int p = 0; p < 4; ++p) {
      int idx = t + p * 256;
      int r = idx >> 4, c4 = (idx & 15) * 4;
      *(float4*)&Ts[r][c4] = *(const float4*)(W + (size_t)(k0 + r) * H_ + n0 + c4);
    }
    __syncthreads();
#pragma unroll
    for (int p = 0; p < 4; ++p) {
      int idx = t + p * 256;
      int rr = idx >> 4, cc = (idx & 15) * 4;   // rr = n-local, cc = k-local
      unsigned short h[4], l[4];
#pragma unroll
      for (int q = 0; q < 4; ++q) {
        float f = Ts[cc + q][rr];
        h[q] = f2bf(f);
        l[q] = f2bf(f - bf2f(h[q]));
      }
      size_t o = (size_t)(n0 + rr) * H_ + k0 + cc;
      *(ushort4*)(Wth + o) = make_ushort4(h[0], h[1], h[2], h[3]);
      *(ushort4*)(Wtl + o) = make_ushort4(l[0], l[1], l[2], l[3]);
    }
  } else {
    const int bb = b - 17408;   // 1024 blocks * 256 threads * 16 B = 4 MiB
    ((float4*)G)[bb * 256 + t] = (float4){0.f, 0.f, 0.f, 0.f};
  }
}

// ------- 3-term split-bf16 MFMA GEMM, reg-double-buffered pipeline -------
// Tile 256x128, BK=32, 512 threads (8 waves as 4x2, wave tile 64x64).
// LDS: 3 x 48 KiB buffers, counted vmcnt(6). TWO register fragment sets.
// R4 fix: sched_barrier(0) BETWEEN LOADSET and MFMASET. R3's VGPR=112
// proved the scheduler sank the ds_reads down to their uses (collapsing
// the double buffer and serializing LDS->MFMA per tile). The pin forces
// reads to issue at tile start (fire-and-forget) while the 48 MFMAs --
// which depend only on the previous tile's registers -- run immediately;
// the LDS pipe (~1540 cyc/CU/tile) drains under the MFMA burst (1862 cyc).
#define TILE_USH 24576            // 48 KiB per tile in ushorts
#define OFF_AH 0                  // 256 rows x 32 ushorts
#define OFF_AL 8192
#define OFF_BH 16384              // 128 rows x 32 ushorts
#define OFF_BL 20480

#define LOADSET(AH, AL, BH, BL, off)                                  \
  do {                                                                \
    const int _o = (off);                                             \
    _Pragma("unroll") for (int i = 0; i < 4; ++i) {                   \
      AH[i] = *(const bf16x8*)&lds[_o + OFF_AH + rA + i * 512];       \
      AL[i] = *(const bf16x8*)&lds[_o + OFF_AL + rA + i * 512];       \
      BH[i] = *(const bf16x8*)&lds[_o + OFF_BH + rB + i * 512];       \
      BL[i] = *(const bf16x8*)&lds[_o + OFF_BL + rB + i * 512];       \
    }                                                                 \
  } while (0)

#define MFMASET(AH, AL, BH, BL)                                                                  \
  do {                                                                                           \
    __builtin_amdgcn_s_setprio(1);                                                               \
    _Pragma("unroll") for (int i = 0; i < 4; ++i)                                                \
        _Pragma("unroll") for (int j = 0; j < 4; ++j) {                                          \
      acc[i][j] = __builtin_amdgcn_mfma_f32_16x16x32_bf16(AH[i], BH[j], acc[i][j], 0, 0, 0);     \
      acc[i][j] = __builtin_amdgcn_mfma_f32_16x16x32_bf16(AH[i], BL[j], acc[i][j], 0, 0, 0);     \
      acc[i][j] = __builtin_amdgcn_mfma_f32_16x16x32_bf16(AL[i], BH[j], acc[i][j], 0, 0, 0);     \
    }                                                                                            \
    __builtin_amdgcn_s_setprio(0);                                                               \
  } while (0)

__global__ __launch_bounds__(512, 2) void k_gemm3(
    const unsigned short* __restrict__ Ah, const unsigned short* __restrict__ Al,
    const unsigned short* __restrict__ Bh, const unsigned short* __restrict__ Bl,
    unsigned short* __restrict__ Eh, unsigned short* __restrict__ El) {
  __shared__ unsigned short lds[3 * TILE_USH];
  const int t = threadIdx.x;
  const int lane = t & 63, wid = t >> 6;     // 8 waves
  const int wm = wid >> 1, wn = wid & 1;     // 4x2 wave grid, wave tile 64x64
  const int l16 = lane & 15, quad = lane >> 4;

  // bijective XCD remap of the 512-block grid
  const int lin = blockIdx.x + (blockIdx.y << 5);
  const int xcd = lin & 7, slot = lin >> 3;
  const int bm = ((xcd >> 1) << 3) + (slot >> 3);   // 0..31
  const int bn = ((xcd & 1) << 3) + (slot & 7);     // 0..15

  // staging addresses (pre-swizzled global source, linear LDS dest)
  const int rl = lane >> 2;
  const int gg8 = (((lane & 3) ^ ((rl >> 1) & 3)) << 3);
  const unsigned short* gAh0 = Ah + (size_t)(bm * 256 + wid * 16 + rl) * H_ + gg8;
  const unsigned short* gAl0 = Al + (size_t)(bm * 256 + wid * 16 + rl) * H_ + gg8;
  const unsigned short* gAh1 = gAh0 + (size_t)128 * H_;
  const unsigned short* gAl1 = gAl0 + (size_t)128 * H_;
  const unsigned short* gBh  = Bh + (size_t)(bn * 128 + wid * 16 + rl) * H_ + gg8;
  const unsigned short* gBl  = Bl + (size_t)(bn * 128 + wid * 16 + rl) * H_ + gg8;
  const int dA0 = wid * 512;        // chunk = 16 rows * 32 ushorts = 1 KiB
  const int dA1 = dA0 + 4096;       // chunk wid+8
  const int dB  = wid * 512;

  // read-side swizzled fragment offsets
  const int colq = ((quad ^ ((l16 >> 1) & 3)) << 3);
  const int rA = (wm * 64 + l16) * 32 + colq;
  const int rB = (wn * 64 + l16) * 32 + colq;

  f32x4 acc[4][4];
#pragma unroll
  for (int i = 0; i < 4; ++i)
#pragma unroll
    for (int j = 0; j < 4; ++j) acc[i][j] = (f32x4)0.f;

  auto stage6 = [&](int bo, int k) {
    glds16(gAh0 + k, &lds[bo + OFF_AH + dA0]);
    glds16(gAh1 + k, &lds[bo + OFF_AH + dA1]);
    glds16(gAl0 + k, &lds[bo + OFF_AL + dA0]);
    glds16(gAl1 + k, &lds[bo + OFF_AL + dA1]);
    glds16(gBh + k,  &lds[bo + OFF_BH + dB]);
    glds16(gBl + k,  &lds[bo + OFF_BL + dB]);
  };

  // prologue: tiles 0,1 in flight; wait tile 0; load its fragments to regs
  stage6(0, 0);
  stage6(TILE_USH, 32);
  asm volatile("s_waitcnt vmcnt(6)" ::: "memory");
  __builtin_amdgcn_s_barrier();
  __builtin_amdgcn_sched_barrier(0);

  bf16x8 ahA[4], alA[4], bhA[4], blA[4];
  bf16x8 ahB[4], alB[4], bhB[4], blB[4];
  LOADSET(ahA, alA, bhA, blA, 0);

  int stage_off = 2 * TILE_USH;   // buffer of tile tt+2 at iter tt
  int read_off  = TILE_USH;       // buffer of tile tt+1 at iter tt

#pragma unroll 1
  for (int tt = 0; tt < 62; tt += 2) {
    // ---- tile tt: prefetch B-set (tile tt+1), compute A-set ----
    stage6(stage_off, (tt + 2) * 32);
    stage_off += TILE_USH; if (stage_off == 3 * TILE_USH) stage_off = 0;
    asm volatile("s_waitcnt vmcnt(6) lgkmcnt(0)" ::: "memory");
    __builtin_amdgcn_s_barrier();
    __builtin_amdgcn_sched_barrier(0);
    LOADSET(ahB, alB, bhB, blB, read_off);
    read_off += TILE_USH; if (read_off == 3 * TILE_USH) read_off = 0;
    __builtin_amdgcn_sched_barrier(0);   // PIN: reads issue before MFMAs
    MFMASET(ahA, alA, bhA, blA);
    // ---- tile tt+1: prefetch A-set (tile tt+2), compute B-set ----
    stage6(stage_off, (tt + 3) * 32);
    stage_off += TILE_USH; if (stage_off == 3 * TILE_USH) stage_off = 0;
    asm volatile("s_waitcnt vmcnt(6) lgkmcnt(0)" ::: "memory");
    __builtin_amdgcn_s_barrier();
    __builtin_amdgcn_sched_barrier(0);
    LOADSET(ahA, alA, bhA, blA, read_off);
    read_off += TILE_USH; if (read_off == 3 * TILE_USH) read_off = 0;
    __builtin_amdgcn_sched_barrier(0);   // PIN: reads issue before MFMAs
    MFMASET(ahB, alB, bhB, blB);
  }

  // tile 62: all loads drained, load tile 63's fragments, compute A-set
  asm volatile("s_waitcnt vmcnt(0) lgkmcnt(0)" ::: "memory");
  __builtin_amdgcn_s_barrier();
  __builtin_amdgcn_sched_barrier(0);
  LOADSET(ahB, alB, bhB, blB, read_off);
  __builtin_amdgcn_sched_barrier(0);     // PIN
  MFMASET(ahA, alA, bhA, blA);
  // tile 63: compute B-set (no loads, no barrier)
  MFMASET(ahB, alB, bhB, blB);

  // epilogue: split-bf16 store of E
#pragma unroll
  for (int i = 0; i < 4; ++i) {
    const int row0 = bm * 256 + wm * 64 + i * 16 + quad * 4;
#pragma unroll
    for (int j = 0; j < 4; ++j) {
      const int col = bn * 128 + wn * 64 + j * 16 + l16;
#pragma unroll
      for (int r = 0; r < 4; ++r) {
        float v = acc[i][j][r];
        unsigned short hh = f2bf(v);
        unsigned short ll = f2bf(v - bf2f(hh));
        Eh[(size_t)(row0 + r) * H_ + col] = hh;
        El[(size_t)(row0 + r) * H_ + col] = ll;
      }
    }
  }
}

// ---- MFMA Gram: G[c] += Eh*Eh^T + Eh*El^T + El*Eh^T; each block does TWO
//      256-wide K chunks (register accumulate) -> atomics halved vs (8,64). ----
__global__ __launch_bounds__(256, 4) void k_gram_mfma(
    const unsigned short* __restrict__ Eh, const unsigned short* __restrict__ El,
    float* __restrict__ G) {
  __shared__ unsigned short sH[128 * 32], sL[128 * 32];
  const int t = threadIdx.x;
  const int kc = blockIdx.x;   // 0..3, each covers K chunks 2*kc, 2*kc+1
  const int cc = blockIdx.y;   // capsule
  const int lane = t & 63, wid = t >> 6;
  const int wm = wid >> 1, wn = wid & 1;
  const int l16 = lane & 15, quad = lane >> 4;

  const int rl = lane >> 2;
  const int gg = (lane & 3) ^ ((rl >> 1) & 3);
  const int c0 = wid * 2, c1 = c0 + 1;
  const unsigned short* gH0 = Eh + (size_t)(cc * 128 + c0 * 16 + rl) * H_ + gg * 8;
  const unsigned short* gH1 = Eh + (size_t)(cc * 128 + c1 * 16 + rl) * H_ + gg * 8;
  const unsigned short* gL0 = El + (size_t)(cc * 128 + c0 * 16 + rl) * H_ + gg * 8;
  const unsigned short* gL1 = El + (size_t)(cc * 128 + c1 * 16 + rl) * H_ + gg * 8;
  unsigned short* lH0 = sH + c0 * 512;
  unsigned short* lH1 = sH + c1 * 512;
  unsigned short* lL0 = sL + c0 * 512;
  unsigned short* lL1 = sL + c1 * 512;

  const int swz = ((l16 >> 1) & 3);
  const int colq = ((quad ^ swz) * 8);

  f32x4 acc[4][4];
#pragma unroll
  for (int i = 0; i < 4; ++i)
#pragma unroll
    for (int j = 0; j < 4; ++j) acc[i][j] = (f32x4)0.f;

  const int kbeg = kc * 512;           // two 256-wide chunks = 512
  for (int k0 = kbeg; k0 < kbeg + 512; k0 += 32) {
    __syncthreads();
    glds16(gH0 + k0, lH0);
    glds16(gH1 + k0, lH1);
    glds16(gL0 + k0, lL0);
    glds16(gL1 + k0, lL1);
    __syncthreads();

    bf16x8 ah[4], al[4], bh[4], bl[4];
#pragma unroll
    for (int i = 0; i < 4; ++i) {
      const int ra = (wm * 64 + i * 16 + l16) * 32;
      const int rb = (wn * 64 + i * 16 + l16) * 32;
      ah[i] = *(const bf16x8*)&sH[ra + colq];
      al[i] = *(const bf16x8*)&sL[ra + colq];
      bh[i] = *(const bf16x8*)&sH[rb + colq];
      bl[i] = *(const bf16x8*)&sL[rb + colq];
    }
#pragma unroll
    for (int i = 0; i < 4; ++i)
#pragma unroll
      for (int j = 0; j < 4; ++j) {
        acc[i][j] = __builtin_amdgcn_mfma_f32_16x16x32_bf16(ah[i], bh[j], acc[i][j], 0, 0, 0);
        acc[i][j] = __builtin_amdgcn_mfma_f32_16x16x32_bf16(ah[i], bl[j], acc[i][j], 0, 0, 0);
        acc[i][j] = __builtin_amdgcn_mfma_f32_16x16x32_bf16(al[i], bh[j], acc[i][j], 0, 0, 0);
      }
  }

  float* Gc = G + (size_t)cc * S_ * S_;
#pragma unroll
  for (int i = 0; i < 4; ++i) {
    const int row0 = wm * 64 + i * 16 + quad * 4;
#pragma unroll
    for (int j = 0; j < 4; ++j) {
      const int col = wn * 64 + j * 16 + l16;
#pragma unroll
      for (int r = 0; r < 4; ++r)
        atomicAdd(&Gc[(row0 + r) * S_ + col], acc[i][j][r]);
    }
  }
}

// ---- fused routing + projection: each block redoes its capsule's routing ----
__global__ void k_out2(const unsigned short* __restrict__ Eh,
                       const unsigned short* __restrict__ El,
                       const float* __restrict__ G, float* __restrict__ out) {
  const int c = blockIdx.y;
  const int s = threadIdx.x & 127;
  __shared__ float dsh[128];
  __shared__ float red[128];
  __shared__ float wsh[128];
  const float* Gc = G + (size_t)c * S_ * S_;
  float b = 0.f;
  for (int it = 0; it < 3; ++it) {
    red[s] = b; __syncthreads();
    for (int off = 64; off > 0; off >>= 1) {
      if (s < off) red[s] = fmaxf(red[s], red[s + off]);
      __syncthreads();
    }
    float mx = red[0]; __syncthreads();
    float ev = expf(b - mx);
    red[s] = ev; __syncthreads();
    for (int off = 64; off > 0; off >>= 1) {
      if (s < off) red[s] = red[s] + red[s + off];
      __syncthreads();
    }
    float Z = red[0]; __syncthreads();
    float d = ev / Z;
    dsh[s] = d; __syncthreads();
    float y = 0.f;   // (G d)_s via symmetric-column reads
#pragma unroll 8
    for (int j = 0; j < S_; ++j) y = fmaf(Gc[j * S_ + s], dsh[j], y);
    red[s] = d * y; __syncthreads();
    for (int off = 64; off > 0; off >>= 1) {
      if (s < off) red[s] = red[s] + red[s + off];
      __syncthreads();
    }
    float sq = red[0]; __syncthreads();
    float coeff = sq / (1.f + sq) / sqrtf(sq + 1e-9f);
    if (it == 2) wsh[s] = coeff * d;
    else b += coeff * y;
  }
  __syncthreads();

  // projection: out[c,h] = sum_s wsh[s] * (Eh+El)[c,s,h], 2 h per thread
  const int h2 = blockIdx.x * 256 + threadIdx.x;   // dword index, grid.x = 4
  const unsigned* Ph = (const unsigned*)(Eh + (size_t)c * S_ * H_) + h2;
  const unsigned* Pl = (const unsigned*)(El + (size_t)c * S_ * H_) + h2;
  float a0 = 0.f, a1 = 0.f;
#pragma unroll 8
  for (int ss = 0; ss < S_; ++ss) {
    unsigned uh = Ph[(size_t)ss * (H_ / 2)];
    unsigned ul = Pl[(size_t)ss * (H_ / 2)];
    a0 = fmaf(wsh[ss], bf2f((unsigned short)uh) + bf2f((unsigned short)ul), a0);
    a1 = fmaf(wsh[ss], bf2f((unsigned short)(uh >> 16)) + bf2f((unsigned short)(ul >> 16)), a1);
  }
  ((float2*)(out + (size_t)c * H_))[h2] = make_float2(a0, a1);
}

extern "C" void kernel_launch(void* const* d_in, const int* in_sizes, int n_in,
                              void* d_out, int out_size, void* d_ws, size_t ws_size,
                              hipStream_t stream) {
  (void)in_sizes; (void)n_in; (void)out_size; (void)ws_size;
  const float* x = (const float*)d_in[0];
  const float* W = (const float*)d_in[1];
  float* out = (float*)d_out;
  char* ws = (char*)d_ws;

  unsigned short* xh  = (unsigned short*)(ws);                 // 32 MiB
  unsigned short* xl  = (unsigned short*)(ws + 33554432);      // 32 MiB
  unsigned short* Wth = (unsigned short*)(ws + 67108864);      // 8 MiB
  unsigned short* Wtl = (unsigned short*)(ws + 75497472);      // 8 MiB
  unsigned short* Eh  = (unsigned short*)(ws + 83886080);      // 32 MiB
  unsigned short* El  = (unsigned short*)(ws + 117440512);     // 32 MiB
  float*          G   = (float*)(ws + 150994944);              // 4 MiB

  k_split_all<<<dim3(18432), 256, 0, stream>>>(x, xh, xl, W, Wth, Wtl, G);
  k_gemm3<<<dim3(32, 16), 512, 0, stream>>>(xh, xl, Wth, Wtl, Eh, El);
  k_gram_mfma<<<dim3(4, 64), 256, 0, stream>>>(Eh, El, G);
  k_out2<<<dim3(4, 64), 256, 0, stream>>>(Eh, El, G, out);
}

// Round 5
// 323.020 us; speedup vs baseline: 1.1534x; 1.0467x over previous
//
#include <hip/hip_runtime.h>

using bf16x8 = __attribute__((ext_vector_type(8))) __bf16;
using f32x4  = __attribute__((ext_vector_type(4))) float;

#define C_ 64
#define S_ 128
#define H_ 2048
#define M_ 8192

__device__ __forceinline__ unsigned short f2bf(float f) {
  unsigned u = __float_as_uint(f);
  u = u + 0x7fffu + ((u >> 16) & 1u);   // RNE
  return (unsigned short)(u >> 16);
}
__device__ __forceinline__ float bf2f(unsigned short h) {
  return __uint_as_float(((unsigned)h) << 16);
}

// async global->LDS, 16 B per lane; LDS dest = uniform base + lane*16
__device__ __forceinline__ void glds16(const unsigned short* g, unsigned short* l) {
  __builtin_amdgcn_global_load_lds(
      (const __attribute__((address_space(1))) void*)g,
      (__attribute__((address_space(3))) void*)l, 16, 0, 0);
}

// ---- fused: split x (blocks 0..16383) | split+transpose W (16384..17407) | zero G ----
__global__ void k_split_all(const float* __restrict__ x,
                            unsigned short* __restrict__ xh,
                            unsigned short* __restrict__ xl,
                            const float* __restrict__ W,
                            unsigned short* __restrict__ Wth,
                            unsigned short* __restrict__ Wtl,
                            float* __restrict__ G) {
  __shared__ float Ts[64][68];
  const int b = blockIdx.x;
  const int t = threadIdx.x;
  if (b < 16384) {
    int idx = b * 256 + t;
    float4 v = ((const float4*)x)[idx];
    float a[4] = {v.x, v.y, v.z, v.w};
    unsigned short h[4], l[4];
#pragma unroll
    for (int q = 0; q < 4; ++q) {
      h[q] = f2bf(a[q]);
      l[q] = f2bf(a[q] - bf2f(h[q]));
    }
    ((ushort4*)xh)[idx] = make_ushort4(h[0], h[1], h[2], h[3]);
    ((ushort4*)xl)[idx] = make_ushort4(l[0], l[1], l[2], l[3]);
  } else if (b < 17408) {
    const int bb = b - 16384;
    const int k0 = (bb & 31) * 64, n0 = (bb >> 5) * 64;
#pragma unroll
    for (int p = 0; p < 4; ++p) {
      int idx = t + p * 256;
      int r = idx >> 4, c4 = (idx & 15) * 4;
      *(float4*)&Ts[r][c4] = *(const float4*)(W + (size_t)(k0 + r) * H_ + n0 + c4);
    }
    __syncthreads();
#pragma unroll
    for (int p = 0; p < 4; ++p) {
      int idx = t + p * 256;
      int rr = idx >> 4, cc = (idx & 15) * 4;   // rr = n-local, cc = k-local
      unsigned short h[4], l[4];
#pragma unroll
      for (int q = 0; q < 4; ++q) {
        float f = Ts[cc + q][rr];
        h[q] = f2bf(f);
        l[q] = f2bf(f - bf2f(h[q]));
      }
      size_t o = (size_t)(n0 + rr) * H_ + k0 + cc;
      *(ushort4*)(Wth + o) = make_ushort4(h[0], h[1], h[2], h[3]);
      *(ushort4*)(Wtl + o) = make_ushort4(l[0], l[1], l[2], l[3]);
    }
  } else {
    const int bb = b - 17408;   // 1024 blocks * 256 threads * 16 B = 4 MiB
    ((float4*)G)[bb * 256 + t] = (float4){0.f, 0.f, 0.f, 0.f};
  }
}

// ------- 3-term split-bf16 MFMA GEMM, 256x256 tile (MFMA-dominant ratio) -------
// R5 theory: per-wave read->MFMA interleave is serial-ish regardless of source
// pipelining (R3/R4: scheduler sinks ds_reads to uses, VGPR=112). So make the
// MFMA phase DOMINATE the LDS phase: 256x256 tile -> per K-tile LDS = 192KB
// reads + 64KB DMA ~ 2816 cyc vs MFMA 3724 cyc (ratio 1.32 vs R3's 0.97).
// 8 waves as 2x4 (wave tile 128x64), 2 LDS buffers (128 KiB), stage for tile
// t+1 issued at tile-t top -> DMA latency fully hidden under 3724-cyc compute.
// grid 32x8 = 256 blocks = exactly one round per CU, no tail. B-frags held in
// regs, A-frags streamed (live ~190 VGPR < 256 cap at 2 waves/SIMD).
#define TILE_USH 32768            // 64 KiB per buffer in ushorts
#define OFF_AH 0                  // 256 rows x 32 ushorts
#define OFF_AL 8192
#define OFF_BH 16384              // 256 rows x 32 ushorts
#define OFF_BL 24576

__global__ __launch_bounds__(512, 2) void k_gemm3(
    const unsigned short* __restrict__ Ah, const unsigned short* __restrict__ Al,
    const unsigned short* __restrict__ Bh, const unsigned short* __restrict__ Bl,
    unsigned short* __restrict__ Eh, unsigned short* __restrict__ El) {
  __shared__ unsigned short lds[2 * TILE_USH];
  const int t = threadIdx.x;
  const int lane = t & 63, wid = t >> 6;     // 8 waves
  const int wm = wid >> 2, wn = wid & 3;     // 2x4 wave grid, wave tile 128x64
  const int l16 = lane & 15, quad = lane >> 4;

  // XCD-aware remap of the 256-block grid: each XCD gets 4 bm x 8 bn
  const int lin = blockIdx.x + (blockIdx.y << 5);
  const int xcd = lin & 7, slot = lin >> 3;   // slot 0..31
  const int bm = xcd * 4 + (slot >> 3);       // 0..31
  const int bn = slot & 7;                    // 0..7

  // staging addresses (pre-swizzled global source, linear LDS dest)
  const int rl = lane >> 2;
  const int gg8 = (((lane & 3) ^ ((rl >> 1) & 3)) << 3);
  const unsigned short* gAh0 = Ah + (size_t)(bm * 256 + wid * 16 + rl) * H_ + gg8;
  const unsigned short* gAl0 = Al + (size_t)(bm * 256 + wid * 16 + rl) * H_ + gg8;
  const unsigned short* gAh1 = gAh0 + (size_t)128 * H_;
  const unsigned short* gAl1 = gAl0 + (size_t)128 * H_;
  const unsigned short* gBh0 = Bh + (size_t)(bn * 256 + wid * 16 + rl) * H_ + gg8;
  const unsigned short* gBl0 = Bl + (size_t)(bn * 256 + wid * 16 + rl) * H_ + gg8;
  const unsigned short* gBh1 = gBh0 + (size_t)128 * H_;
  const unsigned short* gBl1 = gBl0 + (size_t)128 * H_;
  const int dA0 = wid * 512;        // chunk = 16 rows * 32 ushorts = 1 KiB
  const int dA1 = dA0 + 4096;       // chunk wid+8
  const int dB0 = wid * 512;
  const int dB1 = dB0 + 4096;

  // read-side swizzled fragment offsets (same verified 0-conflict pattern)
  const int colq = ((quad ^ ((l16 >> 1) & 3)) << 3);
  const int rA = (wm * 128 + l16) * 32 + colq;
  const int rB = (wn * 64 + l16) * 32 + colq;

  f32x4 acc[8][4];
#pragma unroll
  for (int i = 0; i < 8; ++i)
#pragma unroll
    for (int j = 0; j < 4; ++j) acc[i][j] = (f32x4)0.f;

  auto stage8 = [&](int bo, int k) {
    glds16(gAh0 + k, &lds[bo + OFF_AH + dA0]);
    glds16(gAh1 + k, &lds[bo + OFF_AH + dA1]);
    glds16(gAl0 + k, &lds[bo + OFF_AL + dA0]);
    glds16(gAl1 + k, &lds[bo + OFF_AL + dA1]);
    glds16(gBh0 + k, &lds[bo + OFF_BH + dB0]);
    glds16(gBh1 + k, &lds[bo + OFF_BH + dB1]);
    glds16(gBl0 + k, &lds[bo + OFF_BL + dB0]);
    glds16(gBl1 + k, &lds[bo + OFF_BL + dB1]);
  };

  // prologue: tile 0 staged and landed
  stage8(0, 0);
  asm volatile("s_waitcnt vmcnt(0)" ::: "memory");
  __builtin_amdgcn_s_barrier();

  int cur = 0;
#pragma unroll 1
  for (int tt = 0; tt < 64; ++tt) {
    const int co = cur * TILE_USH;
    if (tt < 63) stage8((cur ^ 1) * TILE_USH, (tt + 1) * 32);  // hidden under compute
    bf16x8 bh[4], bl[4];
#pragma unroll
    for (int j = 0; j < 4; ++j) {
      bh[j] = *(const bf16x8*)&lds[co + OFF_BH + rB + j * 512];
      bl[j] = *(const bf16x8*)&lds[co + OFF_BL + rB + j * 512];
    }
    __builtin_amdgcn_s_setprio(1);
#pragma unroll
    for (int i = 0; i < 8; ++i) {
      bf16x8 ah = *(const bf16x8*)&lds[co + OFF_AH + rA + i * 512];
      bf16x8 al = *(const bf16x8*)&lds[co + OFF_AL + rA + i * 512];
#pragma unroll
      for (int j = 0; j < 4; ++j) {
        acc[i][j] = __builtin_amdgcn_mfma_f32_16x16x32_bf16(ah, bh[j], acc[i][j], 0, 0, 0);
        acc[i][j] = __builtin_amdgcn_mfma_f32_16x16x32_bf16(ah, bl[j], acc[i][j], 0, 0, 0);
        acc[i][j] = __builtin_amdgcn_mfma_f32_16x16x32_bf16(al, bh[j], acc[i][j], 0, 0, 0);
      }
    }
    __builtin_amdgcn_s_setprio(0);
    if (tt < 63) {
      // DMA for tile t+1 has been covered by ~3700 cyc of MFMA; drain + sync
      asm volatile("s_waitcnt vmcnt(0) lgkmcnt(0)" ::: "memory");
      __builtin_amdgcn_s_barrier();
    }
    cur ^= 1;
  }

  // epilogue: split-bf16 store of E
#pragma unroll
  for (int i = 0; i < 8; ++i) {
    const int row0 = bm * 256 + wm * 128 + i * 16 + quad * 4;
#pragma unroll
    for (int j = 0; j < 4; ++j) {
      const int col = bn * 256 + wn * 64 + j * 16 + l16;
#pragma unroll
      for (int r = 0; r < 4; ++r) {
        float v = acc[i][j][r];
        unsigned short hh = f2bf(v);
        unsigned short ll = f2bf(v - bf2f(hh));
        Eh[(size_t)(row0 + r) * H_ + col] = hh;
        El[(size_t)(row0 + r) * H_ + col] = ll;
      }
    }
  }
}

// ---- MFMA Gram: G[c] += Eh*Eh^T + Eh*El^T + El*Eh^T; two 256-wide K chunks
//      per block. R5: double-buffered stage-ahead (DMA latency hidden under
//      the MFMA burst instead of exposed per step). ----
__global__ __launch_bounds__(256, 4) void k_gram_mfma(
    const unsigned short* __restrict__ Eh, const unsigned short* __restrict__ El,
    float* __restrict__ G) {
  __shared__ unsigned short sb[2][16384];   // per buffer: H 8192, L 8192
  const int t = threadIdx.x;
  const int kc = blockIdx.x;   // 0..3, each covers K chunks 2*kc, 2*kc+1
  const int cc = blockIdx.y;   // capsule
  const int lane = t & 63, wid = t >> 6;
  const int wm = wid >> 1, wn = wid & 1;
  const int l16 = lane & 15, quad = lane >> 4;

  const int rl = lane >> 2;
  const int gg = (lane & 3) ^ ((rl >> 1) & 3);
  const int c0 = wid * 2, c1 = c0 + 1;
  const unsigned short* gH0 = Eh + (size_t)(cc * 128 + c0 * 16 + rl) * H_ + gg * 8;
  const unsigned short* gH1 = Eh + (size_t)(cc * 128 + c1 * 16 + rl) * H_ + gg * 8;
  const unsigned short* gL0 = El + (size_t)(cc * 128 + c0 * 16 + rl) * H_ + gg * 8;
  const unsigned short* gL1 = El + (size_t)(cc * 128 + c1 * 16 + rl) * H_ + gg * 8;
  const int dH0 = c0 * 512, dH1 = c1 * 512;

  const int swz = ((l16 >> 1) & 3);
  const int colq = ((quad ^ swz) * 8);

  f32x4 acc[4][4];
#pragma unroll
  for (int i = 0; i < 4; ++i)
#pragma unroll
    for (int j = 0; j < 4; ++j) acc[i][j] = (f32x4)0.f;

  auto stage4 = [&](int buf, int k) {
    glds16(gH0 + k, &sb[buf][dH0]);
    glds16(gH1 + k, &sb[buf][dH1]);
    glds16(gL0 + k, &sb[buf][8192 + dH0]);
    glds16(gL1 + k, &sb[buf][8192 + dH1]);
  };

  const int kbeg = kc * 512;           // two 256-wide chunks = 512
  stage4(0, kbeg);
  asm volatile("s_waitcnt vmcnt(0)" ::: "memory");
  __builtin_amdgcn_s_barrier();

  int cur = 0;
#pragma unroll 1
  for (int s = 0; s < 16; ++s) {
    if (s < 15) stage4(cur ^ 1, kbeg + (s + 1) * 32);
    const unsigned short* sH = &sb[cur][0];
    const unsigned short* sL = &sb[cur][8192];
    bf16x8 ah[4], al[4], bh[4], bl[4];
#pragma unroll
    for (int i = 0; i < 4; ++i) {
      const int ra = (wm * 64 + i * 16 + l16) * 32;
      const int rb = (wn * 64 + i * 16 + l16) * 32;
      ah[i] = *(const bf16x8*)&sH[ra + colq];
      al[i] = *(const bf16x8*)&sL[ra + colq];
      bh[i] = *(const bf16x8*)&sH[rb + colq];
      bl[i] = *(const bf16x8*)&sL[rb + colq];
    }
    __builtin_amdgcn_s_setprio(1);
#pragma unroll
    for (int i = 0; i < 4; ++i)
#pragma unroll
      for (int j = 0; j < 4; ++j) {
        acc[i][j] = __builtin_amdgcn_mfma_f32_16x16x32_bf16(ah[i], bh[j], acc[i][j], 0, 0, 0);
        acc[i][j] = __builtin_amdgcn_mfma_f32_16x16x32_bf16(ah[i], bl[j], acc[i][j], 0, 0, 0);
        acc[i][j] = __builtin_amdgcn_mfma_f32_16x16x32_bf16(al[i], bh[j], acc[i][j], 0, 0, 0);
      }
    __builtin_amdgcn_s_setprio(0);
    if (s < 15) {
      asm volatile("s_waitcnt vmcnt(0) lgkmcnt(0)" ::: "memory");
      __builtin_amdgcn_s_barrier();
    }
    cur ^= 1;
  }

  float* Gc = G + (size_t)cc * S_ * S_;
#pragma unroll
  for (int i = 0; i < 4; ++i) {
    const int row0 = wm * 64 + i * 16 + quad * 4;
#pragma unroll
    for (int j = 0; j < 4; ++j) {
      const int col = wn * 64 + j * 16 + l16;
#pragma unroll
      for (int r = 0; r < 4; ++r)
        atomicAdd(&Gc[(row0 + r) * S_ + col], acc[i][j][r]);
    }
  }
}

// ---- fused routing + projection: each block redoes its capsule's routing ----
__global__ void k_out2(const unsigned short* __restrict__ Eh,
                       const unsigned short* __restrict__ El,
                       const float* __restrict__ G, float* __restrict__ out) {
  const int c = blockIdx.y;
  const int s = threadIdx.x & 127;
  __shared__ float dsh[128];
  __shared__ float red[128];
  __shared__ float wsh[128];
  const float* Gc = G + (size_t)c * S_ * S_;
  float b = 0.f;
  for (int it = 0; it < 3; ++it) {
    red[s] = b; __syncthreads();
    for (int off = 64; off > 0; off >>= 1) {
      if (s < off) red[s] = fmaxf(red[s], red[s + off]);
      __syncthreads();
    }
    float mx = red[0]; __syncthreads();
    float ev = expf(b - mx);
    red[s] = ev; __syncthreads();
    for (int off = 64; off > 0; off >>= 1) {
      if (s < off) red[s] = red[s] + red[s + off];
      __syncthreads();
    }
    float Z = red[0]; __syncthreads();
    float d = ev / Z;
    dsh[s] = d; __syncthreads();
    float y = 0.f;   // (G d)_s via symmetric-column reads
#pragma unroll 8
    for (int j = 0; j < S_; ++j) y = fmaf(Gc[j * S_ + s], dsh[j], y);
    red[s] = d * y; __syncthreads();
    for (int off = 64; off > 0; off >>= 1) {
      if (s < off) red[s] = red[s] + red[s + off];
      __syncthreads();
    }
    float sq = red[0]; __syncthreads();
    float coeff = sq / (1.f + sq) / sqrtf(sq + 1e-9f);
    if (it == 2) wsh[s] = coeff * d;
    else b += coeff * y;
  }
  __syncthreads();

  // projection: out[c,h] = sum_s wsh[s] * (Eh+El)[c,s,h], 2 h per thread
  const int h2 = blockIdx.x * 256 + threadIdx.x;   // dword index, grid.x = 4
  const unsigned* Ph = (const unsigned*)(Eh + (size_t)c * S_ * H_) + h2;
  const unsigned* Pl = (const unsigned*)(El + (size_t)c * S_ * H_) + h2;
  float a0 = 0.f, a1 = 0.f;
#pragma unroll 8
  for (int ss = 0; ss < S_; ++ss) {
    unsigned uh = Ph[(size_t)ss * (H_ / 2)];
    unsigned ul = Pl[(size_t)ss * (H_ / 2)];
    a0 = fmaf(wsh[ss], bf2f((unsigned short)uh) + bf2f((unsigned short)ul), a0);
    a1 = fmaf(wsh[ss], bf2f((unsigned short)(uh >> 16)) + bf2f((unsigned short)(ul >> 16)), a1);
  }
  ((float2*)(out + (size_t)c * H_))[h2] = make_float2(a0, a1);
}

extern "C" void kernel_launch(void* const* d_in, const int* in_sizes, int n_in,
                              void* d_out, int out_size, void* d_ws, size_t ws_size,
                              hipStream_t stream) {
  (void)in_sizes; (void)n_in; (void)out_size; (void)ws_size;
  const float* x = (const float*)d_in[0];
  const float* W = (const float*)d_in[1];
  float* out = (float*)d_out;
  char* ws = (char*)d_ws;

  unsigned short* xh  = (unsigned short*)(ws);                 // 32 MiB
  unsigned short* xl  = (unsigned short*)(ws + 33554432);      // 32 MiB
  unsigned short* Wth = (unsigned short*)(ws + 67108864);      // 8 MiB
  unsigned short* Wtl = (unsigned short*)(ws + 75497472);      // 8 MiB
  unsigned short* Eh  = (unsigned short*)(ws + 83886080);      // 32 MiB
  unsigned short* El  = (unsigned short*)(ws + 117440512);     // 32 MiB
  float*          G   = (float*)(ws + 150994944);              // 4 MiB

  k_split_all<<<dim3(18432), 256, 0, stream>>>(x, xh, xl, W, Wth, Wtl, G);
  k_gemm3<<<dim3(32, 8), 512, 0, stream>>>(xh, xl, Wth, Wtl, Eh, El);
  k_gram_mfma<<<dim3(4, 64), 256, 0, stream>>>(Eh, El, G);
  k_out2<<<dim3(4, 64), 256, 0, stream>>>(Eh, El, G, out);
}